// Round 5
// baseline (648.614 us; speedup 1.0000x reference)
//
#include <hip/hip_runtime.h>

// ADI diffusion B=16, C=8, S=128, 10 steps. Round 14: fused kernel v2 —
// u band persists in LDS across all 10 steps; only 2-row halos are
// exchanged through global memory per step. Round-4 fused v1 (552us) was
// killed by threadfence wbl2/inv on a 17MB dirty set (full u ping-pong via
// HBM at ~460GB/s, 25MB/step). Now dirty set = 2MB halos; coefficients
// re-fetch from L3 after inv (read-only, latency-hideable).
// Geometry proven in round 4: 256 blocks x 512 thr, 129KB LDS, 1 block/CU
// on 256 CUs -> all blocks co-resident, grid barrier deadlock-safe.

constexpr int S_ = 128;
constexpr int RS = 129;             // padded LDS row stride
constexpr float EPSF = 1e-6f;
constexpr int NBLK = 256;

// LDS rows (RS floats each):
//   U [0,64)    persistent u band, row = c*8+ho
//   A [64,128)  y-out (X1 input) / mix-out (X2 input)
//   B [128,192) x1 park
//   C [192,256) x coeff
// head (k=0) reuse: staging 96 rows at [64,160); x@0 out 96 rows at [160,256)
constexpr int OFF_U  = 0;
constexpr int OFF_A  = 64 * RS;
constexpr int OFF_B  = 128 * RS;
constexpr int OFF_C  = 192 * RS;
constexpr int OFF_ST = 64 * RS;
constexpr int OFF_X0 = 160 * RS;
constexpr int POOL   = 256 * RS;    // 132096 B = 129 KB

__device__ unsigned g_cnt = 0;
__device__ unsigned g_gen = 0;

__device__ __forceinline__ void gridbar() {
    __syncthreads();                 // block's stores issued
    if (threadIdx.x == 0) {
        __threadfence();             // wbl2: dirty set is halos only (~2MB)
        unsigned gen = __hip_atomic_load(&g_gen, __ATOMIC_RELAXED,
                                         __HIP_MEMORY_SCOPE_AGENT);
        unsigned old = __hip_atomic_fetch_add(&g_cnt, 1u, __ATOMIC_ACQ_REL,
                                              __HIP_MEMORY_SCOPE_AGENT);
        if (old == NBLK - 1) {
            __hip_atomic_store(&g_cnt, 0u, __ATOMIC_RELAXED,
                               __HIP_MEMORY_SCOPE_AGENT);
            __hip_atomic_fetch_add(&g_gen, 1u, __ATOMIC_RELEASE,
                                   __HIP_MEMORY_SCOPE_AGENT);
        } else {
            while (__hip_atomic_load(&g_gen, __ATOMIC_ACQUIRE,
                                     __HIP_MEMORY_SCOPE_AGENT) == gen)
                __builtin_amdgcn_s_sleep(8);
        }
        __threadfence();             // inv: drop stale L2 lines before reads
    }
    __syncthreads();
}

__device__ __forceinline__ void jrun(const float (&e)[12], const float (&g)[12],
                                     float (&o)[8]) {
    float x1[12];
    #pragma unroll
    for (int i = 1; i <= 10; ++i) x1[i] = fmaf(g[i], e[i - 1] + e[i + 1], e[i]);
    #pragma unroll
    for (int i = 2; i <= 9; ++i) o[i - 2] = fmaf(g[i], x1[i - 1] + x1[i + 1], e[i]);
}

__global__ __launch_bounds__(512, 2) void adi10_kernel(
    const float* __restrict__ u0, float* __restrict__ bws, float* __restrict__ bout,
    const float* __restrict__ ab, const float* __restrict__ atc,
    const float* __restrict__ bbeta, const float* __restrict__ btc,
    const float* __restrict__ cm)
{
    __shared__ float sP[POOL];
    const int tid = threadIdx.x;
    const int b   = blockIdx.x >> 4;
    const int h0  = (blockIdx.x & 15) << 3;
    const float dt2 = 0.0005f;

    for (int k = 0; k < 10; ++k) {
        const bool head = (k == 0);
        const bool tailmix = (k < 9);
        const float t_y = (2 * k + 1) * dt2;
        const float t_x = (2 * k + 2) * dt2;
        const float* src = head ? u0 : ((k & 1) ? bws : bout);
        float* dst = (k & 1) ? bout : bws;   // k=9 (odd) -> bout = d_out

        if (head) {
            // stage 12-row pristine tile into [64,160) (col layout)
            #pragma unroll
            for (int m = 0; m < 2; ++m) {
                const int col = tid + 512 * m;
                const int c = col >> 7, w = col & 127;
                #pragma unroll
                for (int hh = 0; hh < 12; ++hh) {
                    const int gh = h0 - 2 + hh;
                    float v = 0.f;
                    if (gh >= 0 && gh < S_) v = u0[((b * 8 + c) * S_ + gh) * S_ + w];
                    sP[OFF_ST + (c * 12 + hh) * RS + w] = v;
                }
            }
            __syncthreads();
            // mix in place (each (hh,w) point owned by one thread)
            {
                float M[64];
                #pragma unroll
                for (int i = 0; i < 64; ++i) M[i] = cm[i];
                #pragma unroll
                for (int m = 0; m < 3; ++m) {
                    const int p = tid + 512 * m;
                    const int hh = p >> 7, w = p & 127;
                    float v[8], o[8];
                    #pragma unroll
                    for (int c = 0; c < 8; ++c) v[c] = sP[OFF_ST + (c * 12 + hh) * RS + w];
                    #pragma unroll
                    for (int dd = 0; dd < 8; ++dd) {
                        float a = 0.f;
                        #pragma unroll
                        for (int c = 0; c < 8; ++c) a = fmaf(M[dd * 8 + c], v[c], a);
                        o[dd] = a;
                    }
                    #pragma unroll
                    for (int c = 0; c < 8; ++c) sP[OFF_ST + (c * 12 + hh) * RS + w] = o[c];
                }
            }
            __syncthreads();
            // x@0 on 96 rows x 16 runs (alpha = clip(ab), t=0): ST -> X0
            #pragma unroll
            for (int m = 0; m < 3; ++m) {
                const int run = tid + 512 * m;
                const int r96 = run % 96;
                const int wr  = run / 96;
                const int c = r96 / 12, hh = r96 % 12;
                const int gh = h0 - 2 + hh;
                const int w0 = wr * 8;
                const bool rowin = (gh >= 0 && gh < S_);
                float e[12], g[12];
                #pragma unroll
                for (int j = 0; j < 12; ++j) {
                    const int wj = w0 - 2 + j;
                    const bool win = (wj >= 0 && wj < S_);
                    const float dv = win ? sP[OFF_ST + r96 * RS + wj] : 0.f;
                    float co = 0.f;
                    if (rowin && win) {
                        float al = ab[(c * S_ + gh) * S_ + wj];
                        al = fminf(fmaxf(al, EPSF), 10.f);
                        co = al * 0.0005f;
                    }
                    const float nb = (wj == 0 || wj == S_ - 1) ? 1.f : 2.f;
                    const float rb = __builtin_amdgcn_rcpf(fmaf(nb, co, 1.f) + EPSF);
                    e[j] = rb * dv; g[j] = rb * co;
                }
                float o[8]; jrun(e, g, o);
                #pragma unroll
                for (int i = 0; i < 8; ++i) sP[OFF_X0 + r96 * RS + w0 + i] = o[i];
            }
            __syncthreads();
        }

        // ---- Y stage: 1024 (c,w) columns, 2/thread; solve along h in regs.
        // Own 8 rows from LDS (U or head X0); 2+2 halo rows from global.
        #pragma unroll
        for (int m = 0; m < 2; ++m) {
            const int col = tid + 512 * m;
            const int c = col >> 7, w = col & 127;
            float e[12], g[12];
            #pragma unroll
            for (int hh = 0; hh < 12; ++hh) {
                const int gh = h0 - 2 + hh;
                const bool inr = (gh >= 0 && gh < S_);
                const int ghc = inr ? gh : 0;
                float dv;
                if (head)                    dv = sP[OFF_X0 + (c * 12 + hh) * RS + w];
                else if (hh >= 2 && hh < 10) dv = sP[OFF_U + (c * 8 + hh - 2) * RS + w];
                else                         dv = inr ? src[((b * 8 + c) * S_ + ghc) * S_ + w] : 0.f;
                const int gc = (c * S_ + ghc) * S_ + w;
                float be = fmaf(btc[gc], t_y, bbeta[gc]);
                be = fminf(fmaxf(be, EPSF), 10.f);
                const float co = inr ? be * 0.001f : 0.f;
                const float nb = (gh == 0 || gh == S_ - 1) ? 1.f : 2.f;
                const float rb = __builtin_amdgcn_rcpf(fmaf(nb, co, 1.f) + EPSF);
                e[hh] = rb * dv; g[hh] = rb * co;
            }
            float o[8]; jrun(e, g, o);
            #pragma unroll
            for (int i = 0; i < 8; ++i) sP[OFF_A + (c * 8 + i) * RS + w] = o[i];
        }
        // head: Y read [160,256); coeff overwrites [192,256) -> barrier first
        if (head) __syncthreads();
        // x-coeff into C (coalesced point layout)
        #pragma unroll
        for (int m = 0; m < 16; ++m) {
            const int p = tid + 512 * m;
            const int r = p >> 7, w = p & 127;
            const int c = r >> 3, ho = r & 7;
            const int gc = (c * S_ + h0 + ho) * S_ + w;
            float al = fmaf(atc[gc], t_x, ab[gc]);
            al = fminf(fmaxf(al, EPSF), 10.f);
            sP[OFF_C + r * RS + w] = al * 0.0005f;
        }
        __syncthreads();

        // ---- X1: 64 rows x 16 runs, 2/thread
        float rbk[2][12], gk[2][12], xo[2][8];
        #pragma unroll
        for (int m = 0; m < 2; ++m) {
            const int run = tid + 512 * m;
            const int r = run & 63, wr = run >> 6;
            const int w0 = wr * 8;
            float e[12];
            #pragma unroll
            for (int j = 0; j < 12; ++j) {
                const int wj = w0 - 2 + j;
                const bool win = (wj >= 0 && wj < S_);
                const float co = win ? sP[OFF_C + r * RS + wj] : 0.f;
                const float dv = win ? sP[OFF_A + r * RS + wj] : 0.f;
                const float nb = (wj == 0 || wj == S_ - 1) ? 1.f : 2.f;
                const float rb = __builtin_amdgcn_rcpf(fmaf(nb, co, 1.f) + EPSF);
                rbk[m][j] = rb; gk[m][j] = rb * co;
                e[j] = rb * dv;
            }
            jrun(e, gk[m], xo[m]);
        }

        if (tailmix) {
            #pragma unroll
            for (int m = 0; m < 2; ++m) {
                const int run = tid + 512 * m;
                const int r = run & 63, w0m = (run >> 6) * 8;
                #pragma unroll
                for (int i = 0; i < 8; ++i) sP[OFF_B + r * RS + w0m + i] = xo[m][i];
            }
            __syncthreads();
            // mix: 1024 points, 2/thread; read B, write A
            float M[64];
            #pragma unroll
            for (int i = 0; i < 64; ++i) M[i] = cm[i];
            #pragma unroll
            for (int m = 0; m < 2; ++m) {
                const int p = tid + 512 * m;
                const int ho = p >> 7, w = p & 127;
                float v[8], o[8];
                #pragma unroll
                for (int c = 0; c < 8; ++c) v[c] = sP[OFF_B + (c * 8 + ho) * RS + w];
                #pragma unroll
                for (int dd = 0; dd < 8; ++dd) {
                    float a = 0.f;
                    #pragma unroll
                    for (int c = 0; c < 8; ++c) a = fmaf(M[dd * 8 + c], v[c], a);
                    o[dd] = a;
                }
                #pragma unroll
                for (int c = 0; c < 8; ++c) sP[OFF_A + (c * 8 + ho) * RS + w] = o[c];
            }
            __syncthreads();
            // X2: same runs/coeffs; result -> U (persistent) + halo rows global
            #pragma unroll
            for (int m = 0; m < 2; ++m) {
                const int run = tid + 512 * m;
                const int r = run & 63, wr = run >> 6;
                const int w0m = wr * 8;
                const int c = r >> 3, ho = r & 7;
                float e[12];
                #pragma unroll
                for (int j = 0; j < 12; ++j) {
                    const int wj = w0m - 2 + j;
                    const bool win = (wj >= 0 && wj < S_);
                    const float dv = win ? sP[OFF_A + r * RS + wj] : 0.f;
                    e[j] = rbk[m][j] * dv;
                }
                float o[8]; jrun(e, gk[m], o);
                #pragma unroll
                for (int i = 0; i < 8; ++i) sP[OFF_U + r * RS + w0m + i] = o[i];
                if (ho < 2 || ho >= 6) {   // publish band-edge rows only
                    float4* dst4 = (float4*)&dst[((b * 8 + c) * S_ + h0 + ho) * S_ + w0m];
                    dst4[0] = make_float4(o[0], o[1], o[2], o[3]);
                    dst4[1] = make_float4(o[4], o[5], o[6], o[7]);
                }
            }
        } else {
            // k=9: final output = xo, full band to d_out
            #pragma unroll
            for (int m = 0; m < 2; ++m) {
                const int run = tid + 512 * m;
                const int r = run & 63, wr = run >> 6;
                const int w0m = wr * 8;
                const int c = r >> 3, ho = r & 7;
                float4* dst4 = (float4*)&dst[((b * 8 + c) * S_ + h0 + ho) * S_ + w0m];
                dst4[0] = make_float4(xo[m][0], xo[m][1], xo[m][2], xo[m][3]);
                dst4[1] = make_float4(xo[m][4], xo[m][5], xo[m][6], xo[m][7]);
            }
        }

        if (k < 9) gridbar();   // halo visibility for next step
    }
}

extern "C" void kernel_launch(void* const* d_in, const int* in_sizes, int n_in,
                              void* d_out, int out_size, void* d_ws, size_t ws_size,
                              hipStream_t stream) {
    const float* u_in = (const float*)d_in[0];
    const float* ab   = (const float*)d_in[1];
    const float* bbta = (const float*)d_in[2];
    const float* atc  = (const float*)d_in[3];
    const float* btc  = (const float*)d_in[4];
    const float* cm   = (const float*)d_in[5];
    float* uo = (float*)d_out;
    float* uw = (float*)d_ws;     // 8 MB ping buffer

    adi10_kernel<<<dim3(NBLK), dim3(512), 0, stream>>>(u_in, uw, uo, ab, atc,
                                                       bbta, btc, cm);
}

// Round 6
// 332.809 us; speedup vs baseline: 1.9489x; 1.9489x over previous
//
#include <hip/hip_runtime.h>

// ADI diffusion B=16, C=8, S=128, 10 steps. Round 15: PAIR fusion, zero sync.
// Rounds 4/5 proved software grid barriers cost ~55us/step (worse than the
// ~10us hardware dispatch boundary). But the only cross-block dependency is
// a 2-row h-halo per step -> fuse step pairs via redundant halo compute:
// step-A computes 12 valid rows (16-row input window), step-B consumes them
// from LDS and emits the 8-row band. Intermediate never touches global.
// 10 dispatches -> 5. Coefficients recomputed from global (L2-resident)
// instead of LDS-staged. 256 blocks x 512 thr; LDS 115KB head / 99KB generic.

constexpr int S_ = 128;
constexpr int RS = 129;             // padded LDS row stride
constexpr float EPSF = 1e-6f;

// LDS row regions (RS floats each):
//   P  [0,96)    step-A y-out, then step-A final (F); step-B park/mix (64)
//   Q  [96,192)  step-A x1 park/mix; then step-B y-out (64)
//   ST [96,224)  head only: 16-row staged tile (c*16+hh)
constexpr int OFF_P  = 0;
constexpr int OFF_Q  = 96 * RS;
constexpr int OFF_ST = 96 * RS;

template <int N>
__device__ __forceinline__ void jrunN(const float (&e)[N], const float (&g)[N],
                                      float (&o)[N - 4]) {
    // Jacobi-2 == fixed 5-point formula, stencil radius 2 per output.
    float x1[N];
    #pragma unroll
    for (int i = 1; i <= N - 2; ++i) x1[i] = fmaf(g[i], e[i - 1] + e[i + 1], e[i]);
    #pragma unroll
    for (int i = 2; i <= N - 3; ++i) o[i - 2] = fmaf(g[i], x1[i - 1] + x1[i + 1], e[i]);
}

__device__ __forceinline__ float xcoef(const float* __restrict__ ab,
                                       const float* __restrict__ atc,
                                       int gc, float t) {
    float al = fmaf(atc[gc], t, ab[gc]);
    return fminf(fmaxf(al, EPSF), 10.f) * 0.0005f;
}

template <bool HEAD, bool LAST>
__global__ __launch_bounds__(512, 2) void pair_kernel(
    const float* __restrict__ usrc, float* __restrict__ udst,
    const float* __restrict__ ab, const float* __restrict__ atc,
    const float* __restrict__ bbeta, const float* __restrict__ btc,
    const float* __restrict__ cm,
    float t_ya, float t_xa, float t_yb, float t_xb)
{
    constexpr int POOL = HEAD ? 224 * RS : 192 * RS;
    __shared__ float sP[POOL];
    const int tid = threadIdx.x;
    const int b   = blockIdx.x >> 4;
    const int h0  = (blockIdx.x & 15) << 3;

    if (HEAD) {
        // stage 16-row pristine band (gh = h0-4..h0+11) into ST (c*16+hh)
        #pragma unroll
        for (int m = 0; m < 2; ++m) {
            const int col = tid + 512 * m;
            const int c = col >> 7, w = col & 127;
            #pragma unroll
            for (int hh = 0; hh < 16; ++hh) {
                const int gh = h0 - 4 + hh;
                float v = 0.f;
                if (gh >= 0 && gh < S_) v = usrc[((b * 8 + c) * S_ + gh) * S_ + w];
                sP[OFF_ST + (c * 16 + hh) * RS + w] = v;
            }
        }
        __syncthreads();
        // channel mix in place (2048 points, 4/thread)
        {
            float M[64];
            #pragma unroll
            for (int i = 0; i < 64; ++i) M[i] = cm[i];
            #pragma unroll
            for (int m = 0; m < 4; ++m) {
                const int p = tid + 512 * m;
                const int hh = p >> 7, w = p & 127;
                float v[8], o[8];
                #pragma unroll
                for (int c = 0; c < 8; ++c) v[c] = sP[OFF_ST + (c * 16 + hh) * RS + w];
                #pragma unroll
                for (int dd = 0; dd < 8; ++dd) {
                    float a = 0.f;
                    #pragma unroll
                    for (int c = 0; c < 8; ++c) a = fmaf(M[dd * 8 + c], v[c], a);
                    o[dd] = a;
                }
                #pragma unroll
                for (int c = 0; c < 8; ++c) sP[OFF_ST + (c * 16 + hh) * RS + w] = o[c];
            }
        }
        __syncthreads();
        // x@0 in place: 128 rows x 16 runs = 2048 tasks, 4/thread
        float xh[4][8];
        #pragma unroll
        for (int m = 0; m < 4; ++m) {
            const int task = tid + 512 * m;
            const int rr = task & 127, wr = task >> 7;
            const int c = rr >> 4, hh = rr & 15;
            const int gh = h0 - 4 + hh;
            const int ghc = (gh < 0) ? 0 : ((gh >= S_) ? S_ - 1 : gh);
            const bool rowin = (gh >= 0 && gh < S_);
            const int w0 = wr * 8;
            float e[12], g[12];
            #pragma unroll
            for (int j = 0; j < 12; ++j) {
                const int wj = w0 - 2 + j;
                const bool win = (wj >= 0 && wj < S_);
                const float dv = win ? sP[OFF_ST + rr * RS + wj] : 0.f;
                float co = 0.f;
                if (rowin && win) {
                    float al = ab[(c * S_ + gh) * S_ + wj];
                    co = fminf(fmaxf(al, EPSF), 10.f) * 0.0005f;
                }
                const float nb = (wj == 0 || wj == S_ - 1) ? 1.f : 2.f;
                const float rb = __builtin_amdgcn_rcpf(fmaf(nb, co, 1.f) + EPSF);
                e[j] = rb * dv; g[j] = rb * co;
            }
            jrunN<12>(e, g, xh[m]);
        }
        __syncthreads();
        #pragma unroll
        for (int m = 0; m < 4; ++m) {
            const int task = tid + 512 * m;
            const int rr = task & 127, w0 = (task >> 7) * 8;
            #pragma unroll
            for (int i = 0; i < 8; ++i) sP[OFF_ST + rr * RS + w0 + i] = xh[m][i];
        }
        __syncthreads();
    }

    // ==== STEP A ====
    // Y stage: 1024 (c,w) columns, 2/thread; 16-in -> 12-out along h -> P.
    #pragma unroll
    for (int m = 0; m < 2; ++m) {
        const int col = tid + 512 * m;
        const int c = col >> 7, w = col & 127;
        float e[16], g[16];
        #pragma unroll
        for (int hh = 0; hh < 16; ++hh) {
            const int gh = h0 - 4 + hh;
            const bool inr = (gh >= 0 && gh < S_);
            const int ghc = inr ? gh : 0;
            float dv;
            if (HEAD) dv = sP[OFF_ST + (c * 16 + hh) * RS + w];
            else      dv = inr ? usrc[((b * 8 + c) * S_ + ghc) * S_ + w] : 0.f;
            if (HEAD && !inr) dv = 0.f;   // ST garbage rows masked like global
            const int gc = (c * S_ + ghc) * S_ + w;
            float be = fmaf(btc[gc], t_ya, bbeta[gc]);
            be = fminf(fmaxf(be, EPSF), 10.f);
            const float co = inr ? be * 0.001f : 0.f;
            const float nb = (gh == 0 || gh == S_ - 1) ? 1.f : 2.f;
            const float rb = __builtin_amdgcn_rcpf(fmaf(nb, co, 1.f) + EPSF);
            e[hh] = rb * dv; g[hh] = rb * co;
        }
        float o[12]; jrunN<16>(e, g, o);
        #pragma unroll
        for (int i = 0; i < 12; ++i) sP[OFF_P + (c * 12 + i) * RS + w] = o[i];
    }
    __syncthreads();

    // X1-A: 96 rows x 16 runs = 1536 tasks, 3/thread; read P, park -> Q.
    #pragma unroll
    for (int m = 0; m < 3; ++m) {
        const int task = tid + 512 * m;
        const int rr = task % 96, wr = task / 96;
        const int c = rr / 12, ha = rr % 12;
        const int gh = h0 - 2 + ha;
        const int ghc = (gh < 0) ? 0 : ((gh >= S_) ? S_ - 1 : gh);
        const int w0 = wr * 8;
        float e[12], g[12];
        #pragma unroll
        for (int j = 0; j < 12; ++j) {
            const int wj = w0 - 2 + j;
            const bool win = (wj >= 0 && wj < S_);
            const float dv = win ? sP[OFF_P + rr * RS + wj] : 0.f;
            const float co = win ? xcoef(ab, atc, (c * S_ + ghc) * S_ + wj, t_xa) : 0.f;
            const float nb = (wj == 0 || wj == S_ - 1) ? 1.f : 2.f;
            const float rb = __builtin_amdgcn_rcpf(fmaf(nb, co, 1.f) + EPSF);
            e[j] = rb * dv; g[j] = rb * co;
        }
        float o[8]; jrunN<12>(e, g, o);
        #pragma unroll
        for (int i = 0; i < 8; ++i) sP[OFF_Q + rr * RS + w0 + i] = o[i];
    }
    __syncthreads();
    // mix-A in place on Q: 1536 points, 3/thread.
    {
        float M[64];
        #pragma unroll
        for (int i = 0; i < 64; ++i) M[i] = cm[i];
        #pragma unroll
        for (int m = 0; m < 3; ++m) {
            const int p = tid + 512 * m;
            const int ha = p >> 7, w = p & 127;
            float v[8], o[8];
            #pragma unroll
            for (int c = 0; c < 8; ++c) v[c] = sP[OFF_Q + (c * 12 + ha) * RS + w];
            #pragma unroll
            for (int dd = 0; dd < 8; ++dd) {
                float a = 0.f;
                #pragma unroll
                for (int c = 0; c < 8; ++c) a = fmaf(M[dd * 8 + c], v[c], a);
                o[dd] = a;
            }
            #pragma unroll
            for (int c = 0; c < 8; ++c) sP[OFF_Q + (c * 12 + ha) * RS + w] = o[c];
        }
    }
    __syncthreads();
    // X2-A: read Q, recompute coeff (same t_xa), write F = P.
    #pragma unroll
    for (int m = 0; m < 3; ++m) {
        const int task = tid + 512 * m;
        const int rr = task % 96, wr = task / 96;
        const int c = rr / 12, ha = rr % 12;
        const int gh = h0 - 2 + ha;
        const int ghc = (gh < 0) ? 0 : ((gh >= S_) ? S_ - 1 : gh);
        const int w0 = wr * 8;
        float e[12], g[12];
        #pragma unroll
        for (int j = 0; j < 12; ++j) {
            const int wj = w0 - 2 + j;
            const bool win = (wj >= 0 && wj < S_);
            const float dv = win ? sP[OFF_Q + rr * RS + wj] : 0.f;
            const float co = win ? xcoef(ab, atc, (c * S_ + ghc) * S_ + wj, t_xa) : 0.f;
            const float nb = (wj == 0 || wj == S_ - 1) ? 1.f : 2.f;
            const float rb = __builtin_amdgcn_rcpf(fmaf(nb, co, 1.f) + EPSF);
            e[j] = rb * dv; g[j] = rb * co;
        }
        float o[8]; jrunN<12>(e, g, o);
        #pragma unroll
        for (int i = 0; i < 8; ++i) sP[OFF_P + rr * RS + w0 + i] = o[i];
    }
    __syncthreads();

    // ==== STEP B ====
    // Y stage: 12-in (from F=P) -> 8-out along h -> Q rows [0,64).
    #pragma unroll
    for (int m = 0; m < 2; ++m) {
        const int col = tid + 512 * m;
        const int c = col >> 7, w = col & 127;
        float e[12], g[12];
        #pragma unroll
        for (int hh = 0; hh < 12; ++hh) {
            const int gh = h0 - 2 + hh;
            const bool inr = (gh >= 0 && gh < S_);
            const int ghc = inr ? gh : 0;
            const float dv = inr ? sP[OFF_P + (c * 12 + hh) * RS + w] : 0.f;
            const int gc = (c * S_ + ghc) * S_ + w;
            float be = fmaf(btc[gc], t_yb, bbeta[gc]);
            be = fminf(fmaxf(be, EPSF), 10.f);
            const float co = inr ? be * 0.001f : 0.f;
            const float nb = (gh == 0 || gh == S_ - 1) ? 1.f : 2.f;
            const float rb = __builtin_amdgcn_rcpf(fmaf(nb, co, 1.f) + EPSF);
            e[hh] = rb * dv; g[hh] = rb * co;
        }
        float o[8]; jrunN<12>(e, g, o);
        #pragma unroll
        for (int i = 0; i < 8; ++i) sP[OFF_Q + (c * 8 + i) * RS + w] = o[i];
    }
    __syncthreads();

    // X1-B: 64 rows x 16 runs = 1024 tasks, 2/thread; read Q.
    float xo[2][8];
    #pragma unroll
    for (int m = 0; m < 2; ++m) {
        const int task = tid + 512 * m;
        const int r = task & 63, wr = task >> 6;
        const int c = r >> 3, ho = r & 7;
        const int gh = h0 + ho;
        const int w0 = wr * 8;
        float e[12], g[12];
        #pragma unroll
        for (int j = 0; j < 12; ++j) {
            const int wj = w0 - 2 + j;
            const bool win = (wj >= 0 && wj < S_);
            const float dv = win ? sP[OFF_Q + r * RS + wj] : 0.f;
            const float co = win ? xcoef(ab, atc, (c * S_ + gh) * S_ + wj, t_xb) : 0.f;
            const float nb = (wj == 0 || wj == S_ - 1) ? 1.f : 2.f;
            const float rb = __builtin_amdgcn_rcpf(fmaf(nb, co, 1.f) + EPSF);
            e[j] = rb * dv; g[j] = rb * co;
        }
        jrunN<12>(e, g, xo[m]);
    }

    if (LAST) {
        // step 9: no mix; xo is the final output.
        #pragma unroll
        for (int m = 0; m < 2; ++m) {
            const int task = tid + 512 * m;
            const int r = task & 63, wr = task >> 6;
            const int c = r >> 3, ho = r & 7;
            float4* dst4 = (float4*)&udst[((b * 8 + c) * S_ + h0 + ho) * S_ + wr * 8];
            dst4[0] = make_float4(xo[m][0], xo[m][1], xo[m][2], xo[m][3]);
            dst4[1] = make_float4(xo[m][4], xo[m][5], xo[m][6], xo[m][7]);
        }
    } else {
        // park xo -> P rows [0,64) (P dead after B-Y barrier)
        #pragma unroll
        for (int m = 0; m < 2; ++m) {
            const int task = tid + 512 * m;
            const int r = task & 63, w0 = (task >> 6) * 8;
            #pragma unroll
            for (int i = 0; i < 8; ++i) sP[OFF_P + r * RS + w0 + i] = xo[m][i];
        }
        __syncthreads();
        // mix-B in place: 1024 points, 2/thread.
        float M[64];
        #pragma unroll
        for (int i = 0; i < 64; ++i) M[i] = cm[i];
        #pragma unroll
        for (int m = 0; m < 2; ++m) {
            const int p = tid + 512 * m;
            const int ho = p >> 7, w = p & 127;
            float v[8], o[8];
            #pragma unroll
            for (int c = 0; c < 8; ++c) v[c] = sP[OFF_P + (c * 8 + ho) * RS + w];
            #pragma unroll
            for (int dd = 0; dd < 8; ++dd) {
                float a = 0.f;
                #pragma unroll
                for (int c = 0; c < 8; ++c) a = fmaf(M[dd * 8 + c], v[c], a);
                o[dd] = a;
            }
            #pragma unroll
            for (int c = 0; c < 8; ++c) sP[OFF_P + (c * 8 + ho) * RS + w] = o[c];
        }
        __syncthreads();
        // X2-B: read P, recompute coeff (same t_xb), write global.
        #pragma unroll
        for (int m = 0; m < 2; ++m) {
            const int task = tid + 512 * m;
            const int r = task & 63, wr = task >> 6;
            const int c = r >> 3, ho = r & 7;
            const int gh = h0 + ho;
            const int w0 = wr * 8;
            float e[12], g[12];
            #pragma unroll
            for (int j = 0; j < 12; ++j) {
                const int wj = w0 - 2 + j;
                const bool win = (wj >= 0 && wj < S_);
                const float dv = win ? sP[OFF_P + r * RS + wj] : 0.f;
                const float co = win ? xcoef(ab, atc, (c * S_ + gh) * S_ + wj, t_xb) : 0.f;
                const float nb = (wj == 0 || wj == S_ - 1) ? 1.f : 2.f;
                const float rb = __builtin_amdgcn_rcpf(fmaf(nb, co, 1.f) + EPSF);
                e[j] = rb * dv; g[j] = rb * co;
            }
            float o[8]; jrunN<12>(e, g, o);
            float4* dst4 = (float4*)&udst[((b * 8 + c) * S_ + gh) * S_ + w0];
            dst4[0] = make_float4(o[0], o[1], o[2], o[3]);
            dst4[1] = make_float4(o[4], o[5], o[6], o[7]);
        }
    }
}

extern "C" void kernel_launch(void* const* d_in, const int* in_sizes, int n_in,
                              void* d_out, int out_size, void* d_ws, size_t ws_size,
                              hipStream_t stream) {
    const float* u_in = (const float*)d_in[0];
    const float* ab   = (const float*)d_in[1];
    const float* bbta = (const float*)d_in[2];
    const float* atc  = (const float*)d_in[3];
    const float* btc  = (const float*)d_in[4];
    const float* cm   = (const float*)d_in[5];
    float* uo  = (float*)d_out;
    float* uw1 = (float*)d_ws;                       // ping
    float* uw2 = (float*)d_ws + (16 * 8 * 128 * 128); // pong (+8 MiB)

    const dim3 g(256), blk(512);
    const float dt2 = 0.0005f;
    // pair p covers steps 2p (A) and 2p+1 (B):
    //   t_yA=(4p+1)dt2, t_xA=(4p+2)dt2, t_yB=(4p+3)dt2, t_xB=(4p+4)dt2
    pair_kernel<true, false><<<g, blk, 0, stream>>>(u_in, uw1, ab, atc, bbta, btc, cm,
                                                    1 * dt2, 2 * dt2, 3 * dt2, 4 * dt2);
    pair_kernel<false, false><<<g, blk, 0, stream>>>(uw1, uw2, ab, atc, bbta, btc, cm,
                                                     5 * dt2, 6 * dt2, 7 * dt2, 8 * dt2);
    pair_kernel<false, false><<<g, blk, 0, stream>>>(uw2, uw1, ab, atc, bbta, btc, cm,
                                                     9 * dt2, 10 * dt2, 11 * dt2, 12 * dt2);
    pair_kernel<false, false><<<g, blk, 0, stream>>>(uw1, uw2, ab, atc, bbta, btc, cm,
                                                     13 * dt2, 14 * dt2, 15 * dt2, 16 * dt2);
    pair_kernel<false, true><<<g, blk, 0, stream>>>(uw2, uo, ab, atc, bbta, btc, cm,
                                                    17 * dt2, 18 * dt2, 19 * dt2, 20 * dt2);
}

// Round 7
// 182.573 us; speedup vs baseline: 3.5526x; 1.8229x over previous
//
#include <hip/hip_runtime.h>

// ADI diffusion B=16, C=8, S=128, 10 steps. Round 16: pair fusion + LDS
// coeff staging restored. Round-6's 73us/pair regression was the per-tap
// scattered xcoef() global reads (uncoalesced, ~240 loads/thread/pair,
// latency-bound at 18% VALUBusy). This version stages x-coeffs per step
// into LDS region C with coalesced float4 reads (round-9's proven pattern)
// inside the pair-fusion skeleton (10 -> 5 dispatches, intermediate step
// entirely in LDS). LDS: P(96)+Q(96)+C(96) rows = 148.6KB, 1 block/CU.

constexpr int S_ = 128;
constexpr int RS = 129;             // padded LDS row stride (bank = (r+w)%32)
constexpr float EPSF = 1e-6f;

// LDS row regions (RS floats each):
//   P  [0,96)     step-A y-out / step-A final; step-B park+mix (64)
//   Q  [96,192)   step-A x1 park+mix; step-B y-out (64)
//   C  [192,288)  x-coeff for current x-stage (A: 96 rows, B: 64 rows)
//   ST [96,224)   head only: 16-row staged tile (c*16+hh), dead before X1-A
constexpr int OFF_P  = 0;
constexpr int OFF_Q  = 96 * RS;
constexpr int OFF_C  = 192 * RS;
constexpr int OFF_ST = 96 * RS;
constexpr int POOL   = 288 * RS;    // 148,608 B

template <int N>
__device__ __forceinline__ void jrunN(const float (&e)[N], const float (&g)[N],
                                      float (&o)[N - 4]) {
    // Jacobi-2 == fixed 5-point formula, stencil radius 2 per output.
    float x1[N];
    #pragma unroll
    for (int i = 1; i <= N - 2; ++i) x1[i] = fmaf(g[i], e[i - 1] + e[i + 1], e[i]);
    #pragma unroll
    for (int i = 2; i <= N - 3; ++i) o[i - 2] = fmaf(g[i], x1[i - 1] + x1[i + 1], e[i]);
}

template <bool HEAD, bool LAST>
__global__ __launch_bounds__(512, 2) void pair_kernel(
    const float* __restrict__ usrc, float* __restrict__ udst,
    const float* __restrict__ ab, const float* __restrict__ atc,
    const float* __restrict__ bbeta, const float* __restrict__ btc,
    const float* __restrict__ cm,
    float t_ya, float t_xa, float t_yb, float t_xb)
{
    __shared__ float sP[POOL];
    const int tid = threadIdx.x;
    const int b   = blockIdx.x >> 4;
    const int h0  = (blockIdx.x & 15) << 3;

    if (HEAD) {
        // stage 16-row pristine band (gh = h0-4..h0+11) into ST (c*16+hh)
        #pragma unroll
        for (int m = 0; m < 2; ++m) {
            const int col = tid + 512 * m;
            const int c = col >> 7, w = col & 127;
            #pragma unroll
            for (int hh = 0; hh < 16; ++hh) {
                const int gh = h0 - 4 + hh;
                float v = 0.f;
                if (gh >= 0 && gh < S_) v = usrc[((b * 8 + c) * S_ + gh) * S_ + w];
                sP[OFF_ST + (c * 16 + hh) * RS + w] = v;
            }
        }
        __syncthreads();
        // channel mix in place (2048 points, 4/thread)
        {
            float M[64];
            #pragma unroll
            for (int i = 0; i < 64; ++i) M[i] = cm[i];
            #pragma unroll
            for (int m = 0; m < 4; ++m) {
                const int p = tid + 512 * m;
                const int hh = p >> 7, w = p & 127;
                float v[8], o[8];
                #pragma unroll
                for (int c = 0; c < 8; ++c) v[c] = sP[OFF_ST + (c * 16 + hh) * RS + w];
                #pragma unroll
                for (int dd = 0; dd < 8; ++dd) {
                    float a = 0.f;
                    #pragma unroll
                    for (int c = 0; c < 8; ++c) a = fmaf(M[dd * 8 + c], v[c], a);
                    o[dd] = a;
                }
                #pragma unroll
                for (int c = 0; c < 8; ++c) sP[OFF_ST + (c * 16 + hh) * RS + w] = o[c];
            }
        }
        __syncthreads();
        // x@0 in place: 128 rows x 16 runs, 4/thread (one-time scattered ab)
        float xh[4][8];
        #pragma unroll
        for (int m = 0; m < 4; ++m) {
            const int task = tid + 512 * m;
            const int rr = task & 127, wr = task >> 7;
            const int c = rr >> 4, hh = rr & 15;
            const int gh = h0 - 4 + hh;
            const bool rowin = (gh >= 0 && gh < S_);
            const int w0 = wr * 8;
            float e[12], g[12];
            #pragma unroll
            for (int j = 0; j < 12; ++j) {
                const int wj = w0 - 2 + j;
                const bool win = (wj >= 0 && wj < S_);
                const float dv = win ? sP[OFF_ST + rr * RS + wj] : 0.f;
                float co = 0.f;
                if (rowin && win) {
                    float al = ab[(c * S_ + gh) * S_ + wj];
                    co = fminf(fmaxf(al, EPSF), 10.f) * 0.0005f;
                }
                const float nb = (wj == 0 || wj == S_ - 1) ? 1.f : 2.f;
                const float rb = __builtin_amdgcn_rcpf(fmaf(nb, co, 1.f) + EPSF);
                e[j] = rb * dv; g[j] = rb * co;
            }
            jrunN<12>(e, g, xh[m]);
        }
        __syncthreads();
        #pragma unroll
        for (int m = 0; m < 4; ++m) {
            const int task = tid + 512 * m;
            const int rr = task & 127, w0 = (task >> 7) * 8;
            #pragma unroll
            for (int i = 0; i < 8; ++i) sP[OFF_ST + rr * RS + w0 + i] = xh[m][i];
        }
        __syncthreads();
    }

    // ==== STEP A ====
    // Y-A: 1024 (c,w) cols, 2/thread; 16-in -> 12-out along h -> P.
    #pragma unroll
    for (int m = 0; m < 2; ++m) {
        const int col = tid + 512 * m;
        const int c = col >> 7, w = col & 127;
        float e[16], g[16];
        #pragma unroll
        for (int hh = 0; hh < 16; ++hh) {
            const int gh = h0 - 4 + hh;
            const bool inr = (gh >= 0 && gh < S_);
            const int ghc = inr ? gh : 0;
            float dv;
            if (HEAD) dv = sP[OFF_ST + (c * 16 + hh) * RS + w];  // 0 outside
            else      dv = inr ? usrc[((b * 8 + c) * S_ + ghc) * S_ + w] : 0.f;
            const int gc = (c * S_ + ghc) * S_ + w;
            float be = fmaf(btc[gc], t_ya, bbeta[gc]);
            be = fminf(fmaxf(be, EPSF), 10.f);
            const float co = inr ? be * 0.001f : 0.f;
            const float nb = (gh == 0 || gh == S_ - 1) ? 1.f : 2.f;
            const float rb = __builtin_amdgcn_rcpf(fmaf(nb, co, 1.f) + EPSF);
            e[hh] = rb * dv; g[hh] = rb * co;
        }
        float o[12]; jrunN<16>(e, g, o);
        #pragma unroll
        for (int i = 0; i < 12; ++i) sP[OFF_P + (c * 12 + i) * RS + w] = o[i];
    }
    if (HEAD) __syncthreads();   // C-A staging clobbers part of ST below

    // C-A: stage x-coeff (t_xa) on 96 rows, coalesced float4 (6/thread)
    #pragma unroll
    for (int m = 0; m < 6; ++m) {
        const int task = tid + 512 * m;
        const int r = task >> 5;
        const int w4 = (task & 31) << 2;
        const int c = r / 12, ha = r % 12;
        const int gh = h0 - 2 + ha;
        const int ghc = (gh < 0) ? 0 : ((gh >= S_) ? S_ - 1 : gh);
        const int gc = (c * S_ + ghc) * S_ + w4;
        const float4 a4 = *(const float4*)&ab[gc];
        const float4 t4 = *(const float4*)&atc[gc];
        float al;
        al = fmaf(t4.x, t_xa, a4.x); al = fminf(fmaxf(al, EPSF), 10.f);
        sP[OFF_C + r * RS + w4 + 0] = al * 0.0005f;
        al = fmaf(t4.y, t_xa, a4.y); al = fminf(fmaxf(al, EPSF), 10.f);
        sP[OFF_C + r * RS + w4 + 1] = al * 0.0005f;
        al = fmaf(t4.z, t_xa, a4.z); al = fminf(fmaxf(al, EPSF), 10.f);
        sP[OFF_C + r * RS + w4 + 2] = al * 0.0005f;
        al = fmaf(t4.w, t_xa, a4.w); al = fminf(fmaxf(al, EPSF), 10.f);
        sP[OFF_C + r * RS + w4 + 3] = al * 0.0005f;
    }
    __syncthreads();

    // X1-A: 96 rows x 16 runs, 3/thread; read P,C -> park Q.
    #pragma unroll
    for (int m = 0; m < 3; ++m) {
        const int task = tid + 512 * m;
        const int rr = task % 96, wr = task / 96;
        const int w0 = wr * 8;
        float e[12], g[12];
        #pragma unroll
        for (int j = 0; j < 12; ++j) {
            const int wj = w0 - 2 + j;
            const bool win = (wj >= 0 && wj < S_);
            const float co = win ? sP[OFF_C + rr * RS + wj] : 0.f;
            const float dv = win ? sP[OFF_P + rr * RS + wj] : 0.f;
            const float nb = (wj == 0 || wj == S_ - 1) ? 1.f : 2.f;
            const float rb = __builtin_amdgcn_rcpf(fmaf(nb, co, 1.f) + EPSF);
            e[j] = rb * dv; g[j] = rb * co;
        }
        float o[8]; jrunN<12>(e, g, o);
        #pragma unroll
        for (int i = 0; i < 8; ++i) sP[OFF_Q + rr * RS + w0 + i] = o[i];
    }
    __syncthreads();
    // mix-A in place on Q: 1536 points, 3/thread.
    {
        float M[64];
        #pragma unroll
        for (int i = 0; i < 64; ++i) M[i] = cm[i];
        #pragma unroll
        for (int m = 0; m < 3; ++m) {
            const int p = tid + 512 * m;
            const int ha = p >> 7, w = p & 127;
            float v[8], o[8];
            #pragma unroll
            for (int c = 0; c < 8; ++c) v[c] = sP[OFF_Q + (c * 12 + ha) * RS + w];
            #pragma unroll
            for (int dd = 0; dd < 8; ++dd) {
                float a = 0.f;
                #pragma unroll
                for (int c = 0; c < 8; ++c) a = fmaf(M[dd * 8 + c], v[c], a);
                o[dd] = a;
            }
            #pragma unroll
            for (int c = 0; c < 8; ++c) sP[OFF_Q + (c * 12 + ha) * RS + w] = o[c];
        }
    }
    __syncthreads();
    // X2-A: read Q,C -> write P.
    #pragma unroll
    for (int m = 0; m < 3; ++m) {
        const int task = tid + 512 * m;
        const int rr = task % 96, wr = task / 96;
        const int w0 = wr * 8;
        float e[12], g[12];
        #pragma unroll
        for (int j = 0; j < 12; ++j) {
            const int wj = w0 - 2 + j;
            const bool win = (wj >= 0 && wj < S_);
            const float co = win ? sP[OFF_C + rr * RS + wj] : 0.f;
            const float dv = win ? sP[OFF_Q + rr * RS + wj] : 0.f;
            const float nb = (wj == 0 || wj == S_ - 1) ? 1.f : 2.f;
            const float rb = __builtin_amdgcn_rcpf(fmaf(nb, co, 1.f) + EPSF);
            e[j] = rb * dv; g[j] = rb * co;
        }
        float o[8]; jrunN<12>(e, g, o);
        #pragma unroll
        for (int i = 0; i < 8; ++i) sP[OFF_P + rr * RS + w0 + i] = o[i];
    }
    __syncthreads();

    // ==== STEP B ====
    // C-B: stage x-coeff (t_xb) on 64 rows, coalesced float4 (4/thread)
    #pragma unroll
    for (int m = 0; m < 4; ++m) {
        const int task = tid + 512 * m;
        const int r = task >> 5;
        const int w4 = (task & 31) << 2;
        const int c = r >> 3, ho = r & 7;
        const int gc = (c * S_ + h0 + ho) * S_ + w4;
        const float4 a4 = *(const float4*)&ab[gc];
        const float4 t4 = *(const float4*)&atc[gc];
        float al;
        al = fmaf(t4.x, t_xb, a4.x); al = fminf(fmaxf(al, EPSF), 10.f);
        sP[OFF_C + r * RS + w4 + 0] = al * 0.0005f;
        al = fmaf(t4.y, t_xb, a4.y); al = fminf(fmaxf(al, EPSF), 10.f);
        sP[OFF_C + r * RS + w4 + 1] = al * 0.0005f;
        al = fmaf(t4.z, t_xb, a4.z); al = fminf(fmaxf(al, EPSF), 10.f);
        sP[OFF_C + r * RS + w4 + 2] = al * 0.0005f;
        al = fmaf(t4.w, t_xb, a4.w); al = fminf(fmaxf(al, EPSF), 10.f);
        sP[OFF_C + r * RS + w4 + 3] = al * 0.0005f;
    }
    // Y-B: 12-in (P) -> 8-out -> Q rows [0,64). (C/P/Q writes disjoint)
    #pragma unroll
    for (int m = 0; m < 2; ++m) {
        const int col = tid + 512 * m;
        const int c = col >> 7, w = col & 127;
        float e[12], g[12];
        #pragma unroll
        for (int hh = 0; hh < 12; ++hh) {
            const int gh = h0 - 2 + hh;
            const bool inr = (gh >= 0 && gh < S_);
            const int ghc = inr ? gh : 0;
            const float dv = inr ? sP[OFF_P + (c * 12 + hh) * RS + w] : 0.f;
            const int gc = (c * S_ + ghc) * S_ + w;
            float be = fmaf(btc[gc], t_yb, bbeta[gc]);
            be = fminf(fmaxf(be, EPSF), 10.f);
            const float co = inr ? be * 0.001f : 0.f;
            const float nb = (gh == 0 || gh == S_ - 1) ? 1.f : 2.f;
            const float rb = __builtin_amdgcn_rcpf(fmaf(nb, co, 1.f) + EPSF);
            e[hh] = rb * dv; g[hh] = rb * co;
        }
        float o[8]; jrunN<12>(e, g, o);
        #pragma unroll
        for (int i = 0; i < 8; ++i) sP[OFF_Q + (c * 8 + i) * RS + w] = o[i];
    }
    __syncthreads();

    // X1-B: 64 rows x 16 runs, 2/thread; read Q,C.
    float xo[2][8];
    #pragma unroll
    for (int m = 0; m < 2; ++m) {
        const int task = tid + 512 * m;
        const int r = task & 63, wr = task >> 6;
        const int w0 = wr * 8;
        float e[12], g[12];
        #pragma unroll
        for (int j = 0; j < 12; ++j) {
            const int wj = w0 - 2 + j;
            const bool win = (wj >= 0 && wj < S_);
            const float co = win ? sP[OFF_C + r * RS + wj] : 0.f;
            const float dv = win ? sP[OFF_Q + r * RS + wj] : 0.f;
            const float nb = (wj == 0 || wj == S_ - 1) ? 1.f : 2.f;
            const float rb = __builtin_amdgcn_rcpf(fmaf(nb, co, 1.f) + EPSF);
            e[j] = rb * dv; g[j] = rb * co;
        }
        jrunN<12>(e, g, xo[m]);
    }

    if (LAST) {
        // step 9: no mix; xo is the final output.
        #pragma unroll
        for (int m = 0; m < 2; ++m) {
            const int task = tid + 512 * m;
            const int r = task & 63, wr = task >> 6;
            const int c = r >> 3, ho = r & 7;
            float4* dst4 = (float4*)&udst[((b * 8 + c) * S_ + h0 + ho) * S_ + wr * 8];
            dst4[0] = make_float4(xo[m][0], xo[m][1], xo[m][2], xo[m][3]);
            dst4[1] = make_float4(xo[m][4], xo[m][5], xo[m][6], xo[m][7]);
        }
    } else {
        // park xo -> P rows [0,64) (P dead after Y-B barrier)
        #pragma unroll
        for (int m = 0; m < 2; ++m) {
            const int task = tid + 512 * m;
            const int r = task & 63, w0 = (task >> 6) * 8;
            #pragma unroll
            for (int i = 0; i < 8; ++i) sP[OFF_P + r * RS + w0 + i] = xo[m][i];
        }
        __syncthreads();
        // mix-B in place on P[0,64): 1024 points, 2/thread.
        float M[64];
        #pragma unroll
        for (int i = 0; i < 64; ++i) M[i] = cm[i];
        #pragma unroll
        for (int m = 0; m < 2; ++m) {
            const int p = tid + 512 * m;
            const int ho = p >> 7, w = p & 127;
            float v[8], o[8];
            #pragma unroll
            for (int c = 0; c < 8; ++c) v[c] = sP[OFF_P + (c * 8 + ho) * RS + w];
            #pragma unroll
            for (int dd = 0; dd < 8; ++dd) {
                float a = 0.f;
                #pragma unroll
                for (int c = 0; c < 8; ++c) a = fmaf(M[dd * 8 + c], v[c], a);
                o[dd] = a;
            }
            #pragma unroll
            for (int c = 0; c < 8; ++c) sP[OFF_P + (c * 8 + ho) * RS + w] = o[c];
        }
        __syncthreads();
        // X2-B: read P,C -> write global.
        #pragma unroll
        for (int m = 0; m < 2; ++m) {
            const int task = tid + 512 * m;
            const int r = task & 63, wr = task >> 6;
            const int c = r >> 3, ho = r & 7;
            const int w0 = wr * 8;
            float e[12], g[12];
            #pragma unroll
            for (int j = 0; j < 12; ++j) {
                const int wj = w0 - 2 + j;
                const bool win = (wj >= 0 && wj < S_);
                const float co = win ? sP[OFF_C + r * RS + wj] : 0.f;
                const float dv = win ? sP[OFF_P + r * RS + wj] : 0.f;
                const float nb = (wj == 0 || wj == S_ - 1) ? 1.f : 2.f;
                const float rb = __builtin_amdgcn_rcpf(fmaf(nb, co, 1.f) + EPSF);
                e[j] = rb * dv; g[j] = rb * co;
            }
            float o[8]; jrunN<12>(e, g, o);
            float4* dst4 = (float4*)&udst[((b * 8 + c) * S_ + h0 + ho) * S_ + w0];
            dst4[0] = make_float4(o[0], o[1], o[2], o[3]);
            dst4[1] = make_float4(o[4], o[5], o[6], o[7]);
        }
    }
}

extern "C" void kernel_launch(void* const* d_in, const int* in_sizes, int n_in,
                              void* d_out, int out_size, void* d_ws, size_t ws_size,
                              hipStream_t stream) {
    const float* u_in = (const float*)d_in[0];
    const float* ab   = (const float*)d_in[1];
    const float* bbta = (const float*)d_in[2];
    const float* atc  = (const float*)d_in[3];
    const float* btc  = (const float*)d_in[4];
    const float* cm   = (const float*)d_in[5];
    float* uo  = (float*)d_out;
    float* uw1 = (float*)d_ws;                        // ping
    float* uw2 = (float*)d_ws + (16 * 8 * 128 * 128); // pong (+8 MiB)

    const dim3 g(256), blk(512);
    const float dt2 = 0.0005f;
    // pair p covers steps 2p (A) and 2p+1 (B):
    //   t_yA=(4p+1)dt2, t_xA=(4p+2)dt2, t_yB=(4p+3)dt2, t_xB=(4p+4)dt2
    pair_kernel<true, false><<<g, blk, 0, stream>>>(u_in, uw1, ab, atc, bbta, btc, cm,
                                                    1 * dt2, 2 * dt2, 3 * dt2, 4 * dt2);
    pair_kernel<false, false><<<g, blk, 0, stream>>>(uw1, uw2, ab, atc, bbta, btc, cm,
                                                     5 * dt2, 6 * dt2, 7 * dt2, 8 * dt2);
    pair_kernel<false, false><<<g, blk, 0, stream>>>(uw2, uw1, ab, atc, bbta, btc, cm,
                                                     9 * dt2, 10 * dt2, 11 * dt2, 12 * dt2);
    pair_kernel<false, false><<<g, blk, 0, stream>>>(uw1, uw2, ab, atc, bbta, btc, cm,
                                                     13 * dt2, 14 * dt2, 15 * dt2, 16 * dt2);
    pair_kernel<false, true><<<g, blk, 0, stream>>>(uw2, uo, ab, atc, bbta, btc, cm,
                                                    17 * dt2, 18 * dt2, 19 * dt2, 20 * dt2);
}